// Round 3
// baseline (1511.434 us; speedup 1.0000x reference)
//
#include <hip/hip_runtime.h>

#define Tn 2048
#define Dn 2048
#define Hn 32

typedef float f32x4 __attribute__((ext_vector_type(4)));
typedef __bf16 bf16x8 __attribute__((ext_vector_type(8)));
typedef __bf16 bf16x4 __attribute__((ext_vector_type(4)));

__device__ __forceinline__ float waveSum(float v) {
  v += __shfl_xor(v, 1);
  v += __shfl_xor(v, 2);
  v += __shfl_xor(v, 4);
  v += __shfl_xor(v, 8);
  v += __shfl_xor(v, 16);
  v += __shfl_xor(v, 32);
  return v;
}

__device__ __forceinline__ float sigm(float x) { return 1.f / (1.f + expf(-x)); }

__device__ __forceinline__ void gl_lds16(const void* g, void* l) {
  __builtin_amdgcn_global_load_lds(
      (__attribute__((address_space(1))) void*)(g),
      (__attribute__((address_space(3))) void*)(l), 16, 0, 0);
}

// ---------------- weight casts ----------------

__global__ __launch_bounds__(256) void castw3_kernel(
    const float* __restrict__ A, const float* __restrict__ B,
    const float* __restrict__ C, __bf16* __restrict__ o0,
    __bf16* __restrict__ o1, __bf16* __restrict__ o2) {
  const int z = blockIdx.y;
  const float* src = z == 0 ? A : (z == 1 ? B : C);
  __bf16* dst = z == 0 ? o0 : (z == 1 ? o1 : o2);
  const size_t i4 = (size_t)blockIdx.x * 256 + threadIdx.x;
  f32x4 v = *(const f32x4*)(src + i4 * 4);
  bf16x4 o;
  o[0] = (__bf16)v[0]; o[1] = (__bf16)v[1]; o[2] = (__bf16)v[2]; o[3] = (__bf16)v[3];
  ((bf16x4*)dst)[i4] = o;
}

__global__ __launch_bounds__(256) void cast1_kernel(
    const float* __restrict__ src, __bf16* __restrict__ dst) {
  const size_t i4 = (size_t)blockIdx.x * 256 + threadIdx.x;
  f32x4 v = *(const f32x4*)(src + i4 * 4);
  bf16x4 o;
  o[0] = (__bf16)v[0]; o[1] = (__bf16)v[1]; o[2] = (__bf16)v[2]; o[3] = (__bf16)v[3];
  ((bf16x4*)dst)[i4] = o;
}

__global__ __launch_bounds__(256) void castT_kernel(
    const float* __restrict__ w2, const float* __restrict__ a2,
    const float* __restrict__ v2, const float* __restrict__ g2,
    __bf16* __restrict__ w2T, __bf16* __restrict__ a2T,
    __bf16* __restrict__ v2T, __bf16* __restrict__ g2T) {
  const int i = blockIdx.x;   // D index
  const int k = threadIdx.x;
  if (k < 64)  w2T[(size_t)i * 64 + k]  = (__bf16)w2[(size_t)k * Dn + i];
  if (k < 64)  a2T[(size_t)i * 64 + k]  = (__bf16)a2[(size_t)k * Dn + i];
  if (k < 32)  v2T[(size_t)i * 32 + k]  = (__bf16)v2[(size_t)k * Dn + i];
  if (k < 128) g2T[(size_t)i * 128 + k] = (__bf16)g2[(size_t)k * Dn + i];
}

// ---------------- layernorm (ln1) ----------------

__global__ __launch_bounds__(256) void ln_kernel(
    const float* __restrict__ x, const float* __restrict__ lw,
    const float* __restrict__ lb, __bf16* __restrict__ xn,
    float* __restrict__ xn_last) {
  __shared__ float red[8];
  const int t = blockIdx.x, tid = threadIdx.x;
  const int lane = tid & 63, wv = tid >> 6;
  const float* xr = x + (size_t)t * Dn;
  float v[8];
  float s = 0.f;
#pragma unroll
  for (int c = 0; c < 8; ++c) { v[c] = xr[tid + c * 256]; s += v[c]; }
  s = waveSum(s);
  if (lane == 0) red[wv] = s;
  __syncthreads();
  const float mu = (red[0] + red[1] + red[2] + red[3]) * (1.f / (float)Dn);
  float q = 0.f;
#pragma unroll
  for (int c = 0; c < 8; ++c) { float d0 = v[c] - mu; q += d0 * d0; }
  q = waveSum(q);
  if (lane == 0) red[4 + wv] = q;
  __syncthreads();
  const float var = (red[4] + red[5] + red[6] + red[7]) * (1.f / (float)Dn);
  const float rstd = rsqrtf(var + 1e-5f);
#pragma unroll
  for (int c = 0; c < 8; ++c) {
    const int d = tid + c * 256;
    const float y = (v[c] - mu) * rstd * lw[d] + lb[d];
    xn[(size_t)t * Dn + d] = (__bf16)y;
    if (t == Tn - 1) xn_last[d] = y;
  }
}

// ---------------- token-shift mix -> 6 bf16 operands ----------------

__global__ __launch_bounds__(256) void mix_kernel(
    const __bf16* __restrict__ xn, const float* __restrict__ state1,
    const float* __restrict__ cr, const float* __restrict__ cw,
    const float* __restrict__ ck, const float* __restrict__ cv,
    const float* __restrict__ ca, const float* __restrict__ cg,
    __bf16* __restrict__ br, __bf16* __restrict__ bw, __bf16* __restrict__ bk,
    __bf16* __restrict__ bv, __bf16* __restrict__ ba, __bf16* __restrict__ bg) {
  const size_t i4 = (size_t)blockIdx.x * 256 + threadIdx.x;  // quad index
  const int t = (int)(i4 >> 9);
  const int d = (int)(i4 & 511) * 4;
  const bf16x4 cb = ((const bf16x4*)xn)[i4];
  f32x4 cur;
#pragma unroll
  for (int e = 0; e < 4; ++e) cur[e] = (float)cb[e];
  f32x4 prv;
  if (t == 0) {
    prv = *(const f32x4*)(state1 + d);
  } else {
    const bf16x4 pb = ((const bf16x4*)xn)[i4 - 512];
#pragma unroll
    for (int e = 0; e < 4; ++e) prv[e] = (float)pb[e];
  }
  const f32x4 sx = prv - cur;
  auto mix1 = [&](const float* c, __bf16* o) {
    const f32x4 cc = *(const f32x4*)(c + d);
    bf16x4 ob;
#pragma unroll
    for (int e = 0; e < 4; ++e) ob[e] = (__bf16)(cur[e] + sx[e] * cc[e]);
    ((bf16x4*)o)[i4] = ob;
  };
  mix1(cr, br); mix1(cw, bw); mix1(ck, bk);
  mix1(cv, bv); mix1(ca, ba); mix1(cg, bg);
}

// ---------------- MFMA GEMM tile core: C[m,n] = sum_k A[m,k]*B[n,k] ----------------

__device__ __forceinline__ void gemm_tile(const __bf16* __restrict__ A,
                                          const __bf16* __restrict__ B,
                                          int K, int row0, int col0,
                                          f32x4 (&acc)[4][4]) {
  __shared__ __attribute__((aligned(16))) __bf16 As[4096];
  __shared__ __attribute__((aligned(16))) __bf16 Bs[4096];
  const int tid = threadIdx.x;
  const int lane = tid & 63, wid = tid >> 6;
  const int wm = (wid >> 1) * 64, wn = (wid & 1) * 64;
  const int lr = lane & 15, lk = (lane >> 4) * 8;
  for (int kt = 0; kt < K; kt += 32) {
#pragma unroll
    for (int it = 0; it < 2; ++it) {
      const int L = it * 256 + tid;
      const int rr = L >> 2, kc = (L & 3) * 8;
      const int lb = (it * 256 + wid * 64) * 8;
      gl_lds16(A + (size_t)(row0 + rr) * K + (kt + kc), &As[lb]);
      gl_lds16(B + (size_t)(col0 + rr) * K + (kt + kc), &Bs[lb]);
    }
    __syncthreads();
    bf16x8 af[4], bfv[4];
#pragma unroll
    for (int mf = 0; mf < 4; ++mf)
      af[mf] = *(const bf16x8*)&As[(wm + mf * 16 + lr) * 32 + lk];
#pragma unroll
    for (int nf = 0; nf < 4; ++nf)
      bfv[nf] = *(const bf16x8*)&Bs[(wn + nf * 16 + lr) * 32 + lk];
#pragma unroll
    for (int mf = 0; mf < 4; ++mf)
#pragma unroll
      for (int nf = 0; nf < 4; ++nf)
        acc[mf][nf] = __builtin_amdgcn_mfma_f32_16x16x32_bf16(
            af[mf], bfv[nf], acc[mf][nf], 0, 0, 0);
    __syncthreads();
  }
}

// r/k/v fused (z selects), bf16 outputs
__global__ __launch_bounds__(256) void gemm3_kernel(
    const __bf16* __restrict__ A0, const __bf16* __restrict__ A1,
    const __bf16* __restrict__ A2, const __bf16* __restrict__ B0,
    const __bf16* __restrict__ B1, const __bf16* __restrict__ B2,
    __bf16* __restrict__ C0, __bf16* __restrict__ C1, __bf16* __restrict__ C2) {
  const int z = blockIdx.z;
  const __bf16* A = z == 0 ? A0 : (z == 1 ? A1 : A2);
  const __bf16* B = z == 0 ? B0 : (z == 1 ? B1 : B2);
  __bf16* C = z == 0 ? C0 : (z == 1 ? C1 : C2);
  const int row0 = blockIdx.x * 128, col0 = blockIdx.y * 128;
  f32x4 acc[4][4] = {};
  gemm_tile(A, B, Dn, row0, col0, acc);
  const int lane = threadIdx.x & 63, wid = threadIdx.x >> 6;
  const int wm = (wid >> 1) * 64, wn = (wid & 1) * 64;
#pragma unroll
  for (int mf = 0; mf < 4; ++mf) {
    const int r0 = row0 + wm + mf * 16 + ((lane >> 4) << 2);
#pragma unroll
    for (int nf = 0; nf < 4; ++nf) {
      const int c0 = col0 + wn + nf * 16 + (lane & 15);
#pragma unroll
      for (int rg = 0; rg < 4; ++rg)
        C[(size_t)(r0 + rg) * Dn + c0] = (__bf16)acc[mf][nf][rg];
    }
  }
}

// LoRA stage-2 fused (z: 0=w decay, 1=a, 2=v-blend-gate, 3=g), bf16 outputs
__global__ __launch_bounds__(256) void gemm_s2_kernel(
    const __bf16* __restrict__ Aw, const __bf16* __restrict__ Aa,
    const __bf16* __restrict__ Av, const __bf16* __restrict__ Ag,
    const __bf16* __restrict__ Bw, const __bf16* __restrict__ Ba,
    const __bf16* __restrict__ Bv, const __bf16* __restrict__ Bg,
    const float* __restrict__ w0, const float* __restrict__ a0,
    const float* __restrict__ v0, __bf16* __restrict__ Cw,
    __bf16* __restrict__ Ca, __bf16* __restrict__ Cv, __bf16* __restrict__ Cg) {
  const int z = blockIdx.z;
  const __bf16* A = z == 0 ? Aw : (z == 1 ? Aa : (z == 2 ? Av : Ag));
  const __bf16* B = z == 0 ? Bw : (z == 1 ? Ba : (z == 2 ? Bv : Bg));
  const float* bias = z == 0 ? w0 : (z == 1 ? a0 : (z == 2 ? v0 : (const float*)0));
  __bf16* C = z == 0 ? Cw : (z == 1 ? Ca : (z == 2 ? Cv : Cg));
  const int K = z == 0 ? 64 : (z == 1 ? 64 : (z == 2 ? 32 : 128));
  const int row0 = blockIdx.x * 128, col0 = blockIdx.y * 128;
  f32x4 acc[4][4] = {};
  gemm_tile(A, B, K, row0, col0, acc);
  const int lane = threadIdx.x & 63, wid = threadIdx.x >> 6;
  const int wm = (wid >> 1) * 64, wn = (wid & 1) * 64;
#pragma unroll
  for (int mf = 0; mf < 4; ++mf) {
    const int r0 = row0 + wm + mf * 16 + ((lane >> 4) << 2);
#pragma unroll
    for (int nf = 0; nf < 4; ++nf) {
      const int c0 = col0 + wn + nf * 16 + (lane & 15);
#pragma unroll
      for (int rg = 0; rg < 4; ++rg) {
        float val = acc[mf][nf][rg];
        if (z == 0)      val = expf(-0.606531f * sigm(val + bias[c0]));
        else if (z < 3)  val = sigm(val + bias[c0]);
        C[(size_t)(r0 + rg) * Dn + c0] = (__bf16)val;
      }
    }
  }
}

// W_o with residual add, fp32 output
__global__ __launch_bounds__(256) void gemm_wo_kernel(
    const __bf16* __restrict__ A, const __bf16* __restrict__ B,
    const float* __restrict__ xres, float* __restrict__ C) {
  const int row0 = blockIdx.x * 128, col0 = blockIdx.y * 128;
  f32x4 acc[4][4] = {};
  gemm_tile(A, B, Dn, row0, col0, acc);
  const int lane = threadIdx.x & 63, wid = threadIdx.x >> 6;
  const int wm = (wid >> 1) * 64, wn = (wid & 1) * 64;
#pragma unroll
  for (int mf = 0; mf < 4; ++mf) {
    const int r0 = row0 + wm + mf * 16 + ((lane >> 4) << 2);
#pragma unroll
    for (int nf = 0; nf < 4; ++nf) {
      const int c0 = col0 + wn + nf * 16 + (lane & 15);
#pragma unroll
      for (int rg = 0; rg < 4; ++rg)
        C[(size_t)(r0 + rg) * Dn + c0] =
            acc[mf][nf][rg] + xres[(size_t)(r0 + rg) * Dn + c0];
    }
  }
}

// ---------------- LoRA stage-1 (skinny, fp32 accum, 4 paths fused) ----------------

__global__ __launch_bounds__(256) void lora1_kernel(
    const __bf16* __restrict__ Xw, const __bf16* __restrict__ Xa,
    const __bf16* __restrict__ Xv, const __bf16* __restrict__ Xg,
    const float* __restrict__ Uw, const float* __restrict__ Ua,
    const float* __restrict__ Uv, const float* __restrict__ Ug,
    __bf16* __restrict__ Yw, __bf16* __restrict__ Ya,
    __bf16* __restrict__ Yv, __bf16* __restrict__ Yg) {
  __shared__ __bf16 xs[8][2048];
  const int path = blockIdx.y;
  const __bf16* X = path == 0 ? Xw : (path == 1 ? Xa : (path == 2 ? Xv : Xg));
  const float* U  = path == 0 ? Uw : (path == 1 ? Ua : (path == 2 ? Uv : Ug));
  __bf16* Y       = path == 0 ? Yw : (path == 1 ? Ya : (path == 2 ? Yv : Yg));
  const int R  = path == 0 ? 64 : (path == 1 ? 64 : (path == 2 ? 32 : 128));
  const int sh = path == 2 ? 3 : (path == 3 ? 1 : 2);   // log2(256/R)
  const int TPO = 1 << sh;
  const int t0 = blockIdx.x * 8;
  const int tid = threadIdx.x;
  for (int c = 0; c < 64; ++c) {
    const int e = c * 256 + tid;
    xs[e >> 11][e & 2047] = X[(size_t)t0 * Dn + e];
  }
  __syncthreads();
  const int j = tid >> sh, p = tid & (TPO - 1);
  float acc[8] = {0.f, 0.f, 0.f, 0.f, 0.f, 0.f, 0.f, 0.f};
  for (int d = p; d < 2048; d += TPO) {
    const float u = U[(size_t)d * R + j];
    const __bf16* xc = &xs[0][d];
#pragma unroll
    for (int rr = 0; rr < 8; ++rr) acc[rr] += (float)xc[rr * 2048] * u;
  }
  for (int m = TPO >> 1; m; m >>= 1) {
#pragma unroll
    for (int rr = 0; rr < 8; ++rr) acc[rr] += __shfl_xor(acc[rr], m);
  }
  if (p == 0) {
#pragma unroll
    for (int rr = 0; rr < 8; ++rr) {
      float y = acc[rr];
      if (path == 0) y = tanhf(y);
      else if (path == 3) y = sigm(y);
      Y[(size_t)(t0 + rr) * R + j] = (__bf16)y;
    }
  }
}

// ---------------- prep: v-blend, kk-norm, k-mod, ab, bonus dot ----------------

__global__ __launch_bounds__(256) void prep_kernel(
    const __bf16* __restrict__ r, __bf16* __restrict__ k, __bf16* __restrict__ v,
    const __bf16* __restrict__ a, const __bf16* __restrict__ vb,
    const float* __restrict__ v_first, const float* __restrict__ k_k,
    const float* __restrict__ k_a, const float* __restrict__ r_k,
    __bf16* __restrict__ kk_out, __bf16* __restrict__ ab_out,
    float* __restrict__ dot_out) {
  const int t = blockIdx.x;
  const int lane = threadIdx.x & 63, wv = threadIdx.x >> 6;
#pragma unroll 1
  for (int c = 0; c < 8; ++c) {
    const int d = c * 256 + wv * 64 + lane;
    const size_t idx = (size_t)t * Dn + d;
    const float kvv = (float)k[idx];
    const float kh = kvv * k_k[d];
    const float nrm = sqrtf(waveSum(kh * kh)) + 1e-6f;
    const float kkv = kh / nrm;
    const float av = (float)a[idx];
    float vv = (float)v[idx];
    vv = vv + (v_first[idx] - vv) * (float)vb[idx];
    const float kfv = kvv * (1.f + (av - 1.f) * k_a[d]);
    const float dt = waveSum((float)r[idx] * kfv * r_k[d]);
    kk_out[idx] = (__bf16)kkv;
    ab_out[idx] = (__bf16)(kkv * av);
    k[idx] = (__bf16)kfv;
    v[idx] = (__bf16)vv;
    if (lane == 0) dot_out[t * Hn + (d >> 6)] = dt;
  }
}

// ---------------- sequential scan: wave per (h,i) row ----------------

__global__ __launch_bounds__(256) void scan_kernel(
    const __bf16* __restrict__ r, const __bf16* __restrict__ w,
    const __bf16* __restrict__ kf, const __bf16* __restrict__ v,
    const __bf16* __restrict__ kk, const __bf16* __restrict__ ab,
    const float* __restrict__ st_in, __bf16* __restrict__ xo,
    float* __restrict__ st_out) {
  const int h = blockIdx.x;
  const int i = blockIdx.y * 4 + (threadIdx.x >> 6);
  const int j = threadIdx.x & 63;
  float S = st_in[(size_t)h * 4096 + i * 64 + j];
  const size_t vb = (size_t)h * 64 + j;
  const size_t sb = (size_t)h * 64 + i;
  float rj = (float)r[vb], wj = (float)w[vb], kj = (float)kf[vb];
  float kkj = (float)kk[vb], abj = (float)ab[vb];
  float vi = (float)v[sb];
  for (int t = 0; t < Tn; ++t) {
    const int tn = (t + 1 < Tn) ? t + 1 : t;
    const size_t nx = (size_t)tn * Dn;
    const float nr = (float)r[nx + vb], nw = (float)w[nx + vb];
    const float nk = (float)kf[nx + vb], nkk = (float)kk[nx + vb];
    const float nab = (float)ab[nx + vb], nv = (float)v[nx + sb];
    float sa = waveSum(S * kkj);
    S = S * wj - sa * abj + vi * kj;
    float o = waveSum(S * rj);
    if (j == 0) xo[(size_t)t * Dn + sb] = (__bf16)o;
    rj = nr; wj = nw; kj = nk; kkj = nkk; abj = nab; vi = nv;
  }
  st_out[(size_t)h * 4096 + i * 64 + j] = S;
}

// ---------------- post: per-head LN + bonus + gate -> bf16 ----------------

__global__ __launch_bounds__(256) void post_kernel(
    const __bf16* __restrict__ xo, const __bf16* __restrict__ v,
    const __bf16* __restrict__ g, const float* __restrict__ dot,
    const float* __restrict__ lnw, const float* __restrict__ lnb,
    __bf16* __restrict__ out) {
  const int t = blockIdx.x;
  const int lane = threadIdx.x & 63, wv = threadIdx.x >> 6;
#pragma unroll 1
  for (int c = 0; c < 8; ++c) {
    const int d = c * 256 + wv * 64 + lane;
    const size_t idx = (size_t)t * Dn + d;
    const float val = (float)xo[idx];
    const float mu = waveSum(val) * (1.f / 64.f);
    const float ctr = val - mu;
    const float var = waveSum(ctr * ctr) * (1.f / 64.f);
    float y = ctr * rsqrtf(var + 0.00064f);
    y = y * lnw[d] + lnb[d];
    const float res = (y + dot[t * Hn + (d >> 6)] * (float)v[idx]) * (float)g[idx];
    out[idx] = (__bf16)res;
  }
}

// ---------------- launcher ----------------

extern "C" void kernel_launch(void* const* d_in, const int* in_sizes, int n_in,
                              void* d_out, int out_size, void* d_ws, size_t ws_size,
                              hipStream_t stream) {
  (void)in_sizes; (void)n_in; (void)out_size; (void)ws_size;
  const float* x       = (const float*)d_in[0];
  const float* state1  = (const float*)d_in[1];
  const float* state2  = (const float*)d_in[2];
  const float* v_first = (const float*)d_in[3];
  const float* ln1_w   = (const float*)d_in[4];
  const float* ln1_b   = (const float*)d_in[5];
  const float* x_r     = (const float*)d_in[6];
  const float* x_w     = (const float*)d_in[7];
  const float* x_k     = (const float*)d_in[8];
  const float* x_v     = (const float*)d_in[9];
  const float* x_a     = (const float*)d_in[10];
  const float* x_g     = (const float*)d_in[11];
  const float* W_r     = (const float*)d_in[12];
  const float* W_k     = (const float*)d_in[13];
  const float* W_v     = (const float*)d_in[14];
  const float* W_o     = (const float*)d_in[15];
  const float* w1      = (const float*)d_in[16];
  const float* w2      = (const float*)d_in[17];
  const float* w0      = (const float*)d_in[18];
  const float* a1      = (const float*)d_in[19];
  const float* a2      = (const float*)d_in[20];
  const float* a0      = (const float*)d_in[21];
  const float* v1      = (const float*)d_in[22];
  const float* v2      = (const float*)d_in[23];
  const float* v0      = (const float*)d_in[24];
  const float* g1      = (const float*)d_in[25];
  const float* g2      = (const float*)d_in[26];
  const float* k_k     = (const float*)d_in[27];
  const float* k_a     = (const float*)d_in[28];
  const float* r_k     = (const float*)d_in[29];
  const float* lnx_w   = (const float*)d_in[30];
  const float* lnx_b   = (const float*)d_in[31];

  char* p = (char*)d_ws;
  const size_t MB = 1ull << 20;
  // 13 slots x 8 MB (each [T][D] bf16 = 8 MB exactly) + ~2.6 MB smalls = ~107 MB.
  // Slot reuse is lifetime-checked against the serialized launch order:
  //   S0 xn (ln->mix)           -> xobuf (scan->post)
  //   S1 xr (mix->gemm3)        -> Wo_b (cast1->gemm_wo)
  //   S2 xw (mix->lora1)        -> wdec (s2->scan)
  //   S3 xk (mix->gemm3)        -> abuf/a (s2->prep) -> xo_b (post->gemm_wo)
  //   S4 xv (mix->gemm3,lora1)  -> vbl (s2->prep)
  //   S5 xa (mix->lora1)        -> gbuf (s2->post)
  //   S6 xg (mix->lora1)        -> kkbuf (prep->scan)
  //   S7 Wr (castw3->gemm3)     -> abbuf (prep->scan)
  //   S8 Wk, S9 Wv, S10 rbuf, S11 kbuf, S12 vbuf
  __bf16* xn    = (__bf16*)(p + 0 * MB);
  __bf16* xobuf = (__bf16*)(p + 0 * MB);
  __bf16* xr_b  = (__bf16*)(p + 8 * MB);
  __bf16* Wo_b  = (__bf16*)(p + 8 * MB);
  __bf16* xw_b  = (__bf16*)(p + 16 * MB);
  __bf16* wdec  = (__bf16*)(p + 16 * MB);
  __bf16* xk_b  = (__bf16*)(p + 24 * MB);
  __bf16* abuf  = (__bf16*)(p + 24 * MB);
  __bf16* xo_b  = (__bf16*)(p + 24 * MB);
  __bf16* xv_b  = (__bf16*)(p + 32 * MB);
  __bf16* vbl   = (__bf16*)(p + 32 * MB);
  __bf16* xa_b  = (__bf16*)(p + 40 * MB);
  __bf16* gbuf  = (__bf16*)(p + 40 * MB);
  __bf16* xg_b  = (__bf16*)(p + 48 * MB);
  __bf16* kkbuf = (__bf16*)(p + 48 * MB);
  __bf16* Wr_b  = (__bf16*)(p + 56 * MB);
  __bf16* abbuf = (__bf16*)(p + 56 * MB);
  __bf16* Wk_b  = (__bf16*)(p + 64 * MB);
  __bf16* Wv_b  = (__bf16*)(p + 72 * MB);
  __bf16* rbuf  = (__bf16*)(p + 80 * MB);
  __bf16* kbuf  = (__bf16*)(p + 88 * MB);
  __bf16* vbuf  = (__bf16*)(p + 96 * MB);
  char* q = p + 104 * MB;                   // smalls, ~2.6 MB
  __bf16* yw  = (__bf16*)q; q += (size_t)Tn * 64 * 2;
  __bf16* ya  = (__bf16*)q; q += (size_t)Tn * 64 * 2;
  __bf16* yv  = (__bf16*)q; q += (size_t)Tn * 32 * 2;
  __bf16* yg  = (__bf16*)q; q += (size_t)Tn * 128 * 2;
  __bf16* w2T = (__bf16*)q; q += (size_t)Dn * 64 * 2;
  __bf16* a2T = (__bf16*)q; q += (size_t)Dn * 64 * 2;
  __bf16* v2T = (__bf16*)q; q += (size_t)Dn * 32 * 2;
  __bf16* g2T = (__bf16*)q; q += (size_t)Dn * 128 * 2;
  float*  dot = (float*)q;  q += (size_t)Tn * Hn * 4;

  float* out     = (float*)d_out;
  float* out_xnl = out + (size_t)Tn * Dn;
  float* out_st  = out_xnl + Dn;

  castw3_kernel<<<dim3(4096, 3), 256, 0, stream>>>(W_r, W_k, W_v, Wr_b, Wk_b, Wv_b);
  castT_kernel<<<2048, 256, 0, stream>>>(w2, a2, v2, g2, w2T, a2T, v2T, g2T);
  ln_kernel<<<2048, 256, 0, stream>>>(x, ln1_w, ln1_b, xn, out_xnl);
  mix_kernel<<<4096, 256, 0, stream>>>(xn, state1, x_r, x_w, x_k, x_v, x_a, x_g,
                                       xr_b, xw_b, xk_b, xv_b, xa_b, xg_b);
  gemm3_kernel<<<dim3(16, 16, 3), 256, 0, stream>>>(
      xr_b, xk_b, xv_b, Wr_b, Wk_b, Wv_b, rbuf, kbuf, vbuf);
  cast1_kernel<<<4096, 256, 0, stream>>>(W_o, Wo_b);  // S1: after gemm3 read xr_b
  lora1_kernel<<<dim3(256, 4), 256, 0, stream>>>(
      xw_b, xa_b, xv_b, xg_b, w1, a1, v1, g1, yw, ya, yv, yg);
  gemm_s2_kernel<<<dim3(16, 16, 4), 256, 0, stream>>>(
      yw, ya, yv, yg, w2T, a2T, v2T, g2T, w0, a0, v0, wdec, abuf, vbl, gbuf);
  prep_kernel<<<2048, 256, 0, stream>>>(rbuf, kbuf, vbuf, abuf, vbl, v_first,
                                        k_k, k_a, r_k, kkbuf, abbuf, dot);
  scan_kernel<<<dim3(32, 16), 256, 0, stream>>>(
      rbuf, wdec, kbuf, vbuf, kkbuf, abbuf, state2, xobuf, out_st);
  post_kernel<<<2048, 256, 0, stream>>>(xobuf, vbuf, gbuf, dot, lnx_w, lnx_b, xo_b);
  gemm_wo_kernel<<<dim3(16, 16), 256, 0, stream>>>(xo_b, Wo_b, x, out);
}

// Round 5
// 1195.444 us; speedup vs baseline: 1.2643x; 1.2643x over previous
//
#include <hip/hip_runtime.h>

#define Tn 2048
#define Dn 2048
#define Hn 32

typedef float f32x4 __attribute__((ext_vector_type(4)));
typedef __bf16 bf16x8 __attribute__((ext_vector_type(8)));
typedef __bf16 bf16x4 __attribute__((ext_vector_type(4)));

// ---- fast wave-64 sum: DPP row reductions (VALU) + readlane, no DS pipe ----
template <int CTRL>
__device__ __forceinline__ float dpp_add(float x) {
  int xi = __builtin_bit_cast(int, x);
  int sh = __builtin_amdgcn_update_dpp(0, xi, CTRL, 0xf, 0xf, true);
  return x + __builtin_bit_cast(float, sh);
}
__device__ __forceinline__ float rdlane(float x, int l) {
  int xi = __builtin_bit_cast(int, x);
  return __builtin_bit_cast(float, __builtin_amdgcn_readlane(xi, l));
}
// returns wave-uniform sum of v across 64 lanes
__device__ __forceinline__ float waveSum(float v) {
  v = dpp_add<0x111>(v);  // row_shr:1
  v = dpp_add<0x112>(v);  // row_shr:2
  v = dpp_add<0x114>(v);  // row_shr:4
  v = dpp_add<0x118>(v);  // row_shr:8  -> lane 15 of each row = row sum
  return (rdlane(v, 15) + rdlane(v, 31)) + (rdlane(v, 47) + rdlane(v, 63));
}

__device__ __forceinline__ float sigm(float x) { return 1.f / (1.f + expf(-x)); }

__device__ __forceinline__ void gl_lds16(const void* g, void* l) {
  __builtin_amdgcn_global_load_lds(
      (__attribute__((address_space(1))) void*)(g),
      (__attribute__((address_space(3))) void*)(l), 16, 0, 0);
}

// ---------------- weight casts ----------------

__global__ __launch_bounds__(256) void castw3_kernel(
    const float* __restrict__ A, const float* __restrict__ B,
    const float* __restrict__ C, __bf16* __restrict__ o0,
    __bf16* __restrict__ o1, __bf16* __restrict__ o2) {
  const int z = blockIdx.y;
  const float* src = z == 0 ? A : (z == 1 ? B : C);
  __bf16* dst = z == 0 ? o0 : (z == 1 ? o1 : o2);
  const size_t i4 = (size_t)blockIdx.x * 256 + threadIdx.x;
  f32x4 v = *(const f32x4*)(src + i4 * 4);
  bf16x4 o;
  o[0] = (__bf16)v[0]; o[1] = (__bf16)v[1]; o[2] = (__bf16)v[2]; o[3] = (__bf16)v[3];
  ((bf16x4*)dst)[i4] = o;
}

__global__ __launch_bounds__(256) void cast1_kernel(
    const float* __restrict__ src, __bf16* __restrict__ dst) {
  const size_t i4 = (size_t)blockIdx.x * 256 + threadIdx.x;
  f32x4 v = *(const f32x4*)(src + i4 * 4);
  bf16x4 o;
  o[0] = (__bf16)v[0]; o[1] = (__bf16)v[1]; o[2] = (__bf16)v[2]; o[3] = (__bf16)v[3];
  ((bf16x4*)dst)[i4] = o;
}

__global__ __launch_bounds__(256) void castT_kernel(
    const float* __restrict__ w2, const float* __restrict__ a2,
    const float* __restrict__ v2, const float* __restrict__ g2,
    __bf16* __restrict__ w2T, __bf16* __restrict__ a2T,
    __bf16* __restrict__ v2T, __bf16* __restrict__ g2T) {
  const int i = blockIdx.x;   // D index
  const int k = threadIdx.x;
  if (k < 64)  w2T[(size_t)i * 64 + k]  = (__bf16)w2[(size_t)k * Dn + i];
  if (k < 64)  a2T[(size_t)i * 64 + k]  = (__bf16)a2[(size_t)k * Dn + i];
  if (k < 32)  v2T[(size_t)i * 32 + k]  = (__bf16)v2[(size_t)k * Dn + i];
  if (k < 128) g2T[(size_t)i * 128 + k] = (__bf16)g2[(size_t)k * Dn + i];
}

// ---------------- layernorm (ln1) ----------------

__global__ __launch_bounds__(256) void ln_kernel(
    const float* __restrict__ x, const float* __restrict__ lw,
    const float* __restrict__ lb, __bf16* __restrict__ xn,
    float* __restrict__ xn_last) {
  __shared__ float red[8];
  const int t = blockIdx.x, tid = threadIdx.x;
  const int lane = tid & 63, wv = tid >> 6;
  const float* xr = x + (size_t)t * Dn;
  float v[8];
  float s = 0.f;
#pragma unroll
  for (int c = 0; c < 8; ++c) { v[c] = xr[tid + c * 256]; s += v[c]; }
  s = waveSum(s);
  if (lane == 0) red[wv] = s;
  __syncthreads();
  const float mu = (red[0] + red[1] + red[2] + red[3]) * (1.f / (float)Dn);
  float q = 0.f;
#pragma unroll
  for (int c = 0; c < 8; ++c) { float d0 = v[c] - mu; q += d0 * d0; }
  q = waveSum(q);
  if (lane == 0) red[4 + wv] = q;
  __syncthreads();
  const float var = (red[4] + red[5] + red[6] + red[7]) * (1.f / (float)Dn);
  const float rstd = rsqrtf(var + 1e-5f);
#pragma unroll
  for (int c = 0; c < 8; ++c) {
    const int d = tid + c * 256;
    const float y = (v[c] - mu) * rstd * lw[d] + lb[d];
    xn[(size_t)t * Dn + d] = (__bf16)y;
    if (t == Tn - 1) xn_last[d] = y;
  }
}

// ---------------- token-shift mix -> 6 bf16 operands ----------------

__global__ __launch_bounds__(256) void mix_kernel(
    const __bf16* __restrict__ xn, const float* __restrict__ state1,
    const float* __restrict__ cr, const float* __restrict__ cw,
    const float* __restrict__ ck, const float* __restrict__ cv,
    const float* __restrict__ ca, const float* __restrict__ cg,
    __bf16* __restrict__ br, __bf16* __restrict__ bw, __bf16* __restrict__ bk,
    __bf16* __restrict__ bv, __bf16* __restrict__ ba, __bf16* __restrict__ bg) {
  const size_t i4 = (size_t)blockIdx.x * 256 + threadIdx.x;  // quad index
  const int t = (int)(i4 >> 9);
  const int d = (int)(i4 & 511) * 4;
  const bf16x4 cb = ((const bf16x4*)xn)[i4];
  f32x4 cur;
#pragma unroll
  for (int e = 0; e < 4; ++e) cur[e] = (float)cb[e];
  f32x4 prv;
  if (t == 0) {
    prv = *(const f32x4*)(state1 + d);
  } else {
    const bf16x4 pb = ((const bf16x4*)xn)[i4 - 512];
#pragma unroll
    for (int e = 0; e < 4; ++e) prv[e] = (float)pb[e];
  }
  const f32x4 sx = prv - cur;
  auto mix1 = [&](const float* c, __bf16* o) {
    const f32x4 cc = *(const f32x4*)(c + d);
    bf16x4 ob;
#pragma unroll
    for (int e = 0; e < 4; ++e) ob[e] = (__bf16)(cur[e] + sx[e] * cc[e]);
    ((bf16x4*)o)[i4] = ob;
  };
  mix1(cr, br); mix1(cw, bw); mix1(ck, bk);
  mix1(cv, bv); mix1(ca, ba); mix1(cg, bg);
}

// ---------------- MFMA GEMM tile core: C[m,n] = sum_k A[m,k]*B[n,k] ----------------

__device__ __forceinline__ void gemm_tile(const __bf16* __restrict__ A,
                                          const __bf16* __restrict__ B,
                                          int K, int row0, int col0,
                                          f32x4 (&acc)[4][4]) {
  __shared__ __attribute__((aligned(16))) __bf16 As[4096];
  __shared__ __attribute__((aligned(16))) __bf16 Bs[4096];
  const int tid = threadIdx.x;
  const int lane = tid & 63, wid = tid >> 6;
  const int wm = (wid >> 1) * 64, wn = (wid & 1) * 64;
  const int lr = lane & 15, lk = (lane >> 4) * 8;
  for (int kt = 0; kt < K; kt += 32) {
#pragma unroll
    for (int it = 0; it < 2; ++it) {
      const int L = it * 256 + tid;
      const int rr = L >> 2, kc = (L & 3) * 8;
      const int lb = (it * 256 + wid * 64) * 8;
      gl_lds16(A + (size_t)(row0 + rr) * K + (kt + kc), &As[lb]);
      gl_lds16(B + (size_t)(col0 + rr) * K + (kt + kc), &Bs[lb]);
    }
    __syncthreads();
    bf16x8 af[4], bfv[4];
#pragma unroll
    for (int mf = 0; mf < 4; ++mf)
      af[mf] = *(const bf16x8*)&As[(wm + mf * 16 + lr) * 32 + lk];
#pragma unroll
    for (int nf = 0; nf < 4; ++nf)
      bfv[nf] = *(const bf16x8*)&Bs[(wn + nf * 16 + lr) * 32 + lk];
#pragma unroll
    for (int mf = 0; mf < 4; ++mf)
#pragma unroll
      for (int nf = 0; nf < 4; ++nf)
        acc[mf][nf] = __builtin_amdgcn_mfma_f32_16x16x32_bf16(
            af[mf], bfv[nf], acc[mf][nf], 0, 0, 0);
    __syncthreads();
  }
}

// r/k/v fused (z selects), bf16 outputs
__global__ __launch_bounds__(256) void gemm3_kernel(
    const __bf16* __restrict__ A0, const __bf16* __restrict__ A1,
    const __bf16* __restrict__ A2, const __bf16* __restrict__ B0,
    const __bf16* __restrict__ B1, const __bf16* __restrict__ B2,
    __bf16* __restrict__ C0, __bf16* __restrict__ C1, __bf16* __restrict__ C2) {
  const int z = blockIdx.z;
  const __bf16* A = z == 0 ? A0 : (z == 1 ? A1 : A2);
  const __bf16* B = z == 0 ? B0 : (z == 1 ? B1 : B2);
  __bf16* C = z == 0 ? C0 : (z == 1 ? C1 : C2);
  const int row0 = blockIdx.x * 128, col0 = blockIdx.y * 128;
  f32x4 acc[4][4] = {};
  gemm_tile(A, B, Dn, row0, col0, acc);
  const int lane = threadIdx.x & 63, wid = threadIdx.x >> 6;
  const int wm = (wid >> 1) * 64, wn = (wid & 1) * 64;
#pragma unroll
  for (int mf = 0; mf < 4; ++mf) {
    const int r0 = row0 + wm + mf * 16 + ((lane >> 4) << 2);
#pragma unroll
    for (int nf = 0; nf < 4; ++nf) {
      const int c0 = col0 + wn + nf * 16 + (lane & 15);
#pragma unroll
      for (int rg = 0; rg < 4; ++rg)
        C[(size_t)(r0 + rg) * Dn + c0] = (__bf16)acc[mf][nf][rg];
    }
  }
}

// LoRA stage-2 fused (z: 0=w decay, 1=a, 2=v-blend-gate, 3=g), bf16 outputs
__global__ __launch_bounds__(256) void gemm_s2_kernel(
    const __bf16* __restrict__ Aw, const __bf16* __restrict__ Aa,
    const __bf16* __restrict__ Av, const __bf16* __restrict__ Ag,
    const __bf16* __restrict__ Bw, const __bf16* __restrict__ Ba,
    const __bf16* __restrict__ Bv, const __bf16* __restrict__ Bg,
    const float* __restrict__ w0, const float* __restrict__ a0,
    const float* __restrict__ v0, __bf16* __restrict__ Cw,
    __bf16* __restrict__ Ca, __bf16* __restrict__ Cv, __bf16* __restrict__ Cg) {
  const int z = blockIdx.z;
  const __bf16* A = z == 0 ? Aw : (z == 1 ? Aa : (z == 2 ? Av : Ag));
  const __bf16* B = z == 0 ? Bw : (z == 1 ? Ba : (z == 2 ? Bv : Bg));
  const float* bias = z == 0 ? w0 : (z == 1 ? a0 : (z == 2 ? v0 : (const float*)0));
  __bf16* C = z == 0 ? Cw : (z == 1 ? Ca : (z == 2 ? Cv : Cg));
  const int K = z == 0 ? 64 : (z == 1 ? 64 : (z == 2 ? 32 : 128));
  const int row0 = blockIdx.x * 128, col0 = blockIdx.y * 128;
  f32x4 acc[4][4] = {};
  gemm_tile(A, B, K, row0, col0, acc);
  const int lane = threadIdx.x & 63, wid = threadIdx.x >> 6;
  const int wm = (wid >> 1) * 64, wn = (wid & 1) * 64;
#pragma unroll
  for (int mf = 0; mf < 4; ++mf) {
    const int r0 = row0 + wm + mf * 16 + ((lane >> 4) << 2);
#pragma unroll
    for (int nf = 0; nf < 4; ++nf) {
      const int c0 = col0 + wn + nf * 16 + (lane & 15);
#pragma unroll
      for (int rg = 0; rg < 4; ++rg) {
        float val = acc[mf][nf][rg];
        if (z == 0)      val = expf(-0.606531f * sigm(val + bias[c0]));
        else if (z < 3)  val = sigm(val + bias[c0]);
        C[(size_t)(r0 + rg) * Dn + c0] = (__bf16)val;
      }
    }
  }
}

// W_o with residual add, fp32 output
__global__ __launch_bounds__(256) void gemm_wo_kernel(
    const __bf16* __restrict__ A, const __bf16* __restrict__ B,
    const float* __restrict__ xres, float* __restrict__ C) {
  const int row0 = blockIdx.x * 128, col0 = blockIdx.y * 128;
  f32x4 acc[4][4] = {};
  gemm_tile(A, B, Dn, row0, col0, acc);
  const int lane = threadIdx.x & 63, wid = threadIdx.x >> 6;
  const int wm = (wid >> 1) * 64, wn = (wid & 1) * 64;
#pragma unroll
  for (int mf = 0; mf < 4; ++mf) {
    const int r0 = row0 + wm + mf * 16 + ((lane >> 4) << 2);
#pragma unroll
    for (int nf = 0; nf < 4; ++nf) {
      const int c0 = col0 + wn + nf * 16 + (lane & 15);
#pragma unroll
      for (int rg = 0; rg < 4; ++rg)
        C[(size_t)(r0 + rg) * Dn + c0] =
            acc[mf][nf][rg] + xres[(size_t)(r0 + rg) * Dn + c0];
    }
  }
}

// ---------------- LoRA stage-1 (skinny, fp32 accum, 4 paths fused) ----------------

__global__ __launch_bounds__(256) void lora1_kernel(
    const __bf16* __restrict__ Xw, const __bf16* __restrict__ Xa,
    const __bf16* __restrict__ Xv, const __bf16* __restrict__ Xg,
    const float* __restrict__ Uw, const float* __restrict__ Ua,
    const float* __restrict__ Uv, const float* __restrict__ Ug,
    __bf16* __restrict__ Yw, __bf16* __restrict__ Ya,
    __bf16* __restrict__ Yv, __bf16* __restrict__ Yg) {
  __shared__ __bf16 xs[8][2048];
  const int path = blockIdx.y;
  const __bf16* X = path == 0 ? Xw : (path == 1 ? Xa : (path == 2 ? Xv : Xg));
  const float* U  = path == 0 ? Uw : (path == 1 ? Ua : (path == 2 ? Uv : Ug));
  __bf16* Y       = path == 0 ? Yw : (path == 1 ? Ya : (path == 2 ? Yv : Yg));
  const int R  = path == 0 ? 64 : (path == 1 ? 64 : (path == 2 ? 32 : 128));
  const int sh = path == 2 ? 3 : (path == 3 ? 1 : 2);   // log2(256/R)
  const int TPO = 1 << sh;
  const int t0 = blockIdx.x * 8;
  const int tid = threadIdx.x;
  for (int c = 0; c < 64; ++c) {
    const int e = c * 256 + tid;
    xs[e >> 11][e & 2047] = X[(size_t)t0 * Dn + e];
  }
  __syncthreads();
  const int j = tid >> sh, p = tid & (TPO - 1);
  float acc[8] = {0.f, 0.f, 0.f, 0.f, 0.f, 0.f, 0.f, 0.f};
  for (int d = p; d < 2048; d += TPO) {
    const float u = U[(size_t)d * R + j];
    const __bf16* xc = &xs[0][d];
#pragma unroll
    for (int rr = 0; rr < 8; ++rr) acc[rr] += (float)xc[rr * 2048] * u;
  }
  for (int m = TPO >> 1; m; m >>= 1) {
#pragma unroll
    for (int rr = 0; rr < 8; ++rr) acc[rr] += __shfl_xor(acc[rr], m);
  }
  if (p == 0) {
#pragma unroll
    for (int rr = 0; rr < 8; ++rr) {
      float y = acc[rr];
      if (path == 0) y = tanhf(y);
      else if (path == 3) y = sigm(y);
      Y[(size_t)(t0 + rr) * R + j] = (__bf16)y;
    }
  }
}

// ---------------- prep: v-blend, kk-norm, k-mod, ab, bonus dot ----------------

__global__ __launch_bounds__(256) void prep_kernel(
    const __bf16* __restrict__ r, __bf16* __restrict__ k, __bf16* __restrict__ v,
    const __bf16* __restrict__ a, const __bf16* __restrict__ vb,
    const float* __restrict__ v_first, const float* __restrict__ k_k,
    const float* __restrict__ k_a, const float* __restrict__ r_k,
    __bf16* __restrict__ kk_out, __bf16* __restrict__ ab_out,
    float* __restrict__ dot_out) {
  const int t = blockIdx.x;
  const int lane = threadIdx.x & 63, wv = threadIdx.x >> 6;
#pragma unroll 1
  for (int c = 0; c < 8; ++c) {
    const int d = c * 256 + wv * 64 + lane;
    const size_t idx = (size_t)t * Dn + d;
    const float kvv = (float)k[idx];
    const float kh = kvv * k_k[d];
    const float nrm = sqrtf(waveSum(kh * kh)) + 1e-6f;
    const float kkv = kh / nrm;
    const float av = (float)a[idx];
    float vv = (float)v[idx];
    vv = vv + (v_first[idx] - vv) * (float)vb[idx];
    const float kfv = kvv * (1.f + (av - 1.f) * k_a[d]);
    const float dt = waveSum((float)r[idx] * kfv * r_k[d]);
    kk_out[idx] = (__bf16)kkv;
    ab_out[idx] = (__bf16)(kkv * av);
    k[idx] = (__bf16)kfv;
    v[idx] = (__bf16)vv;
    if (lane == 0) dot_out[t * Hn + (d >> 6)] = dt;
  }
}

// ---------------- sequential scan: wave per (h,i) row ----------------

__global__ __launch_bounds__(256) void scan_kernel(
    const __bf16* __restrict__ r, const __bf16* __restrict__ w,
    const __bf16* __restrict__ kf, const __bf16* __restrict__ v,
    const __bf16* __restrict__ kk, const __bf16* __restrict__ ab,
    const float* __restrict__ st_in, __bf16* __restrict__ xo,
    float* __restrict__ st_out) {
  const int h = blockIdx.x;
  const int i = blockIdx.y * 4 + (threadIdx.x >> 6);
  const int j = threadIdx.x & 63;
  float S = st_in[(size_t)h * 4096 + i * 64 + j];
  const size_t vb = (size_t)h * 64 + j;
  const size_t sb = (size_t)h * 64 + i;
  float rj = (float)r[vb], wj = (float)w[vb], kj = (float)kf[vb];
  float kkj = (float)kk[vb], abj = (float)ab[vb];
  float vi = (float)v[sb];
  for (int t = 0; t < Tn; ++t) {
    const int tn = (t + 1 < Tn) ? t + 1 : t;
    const size_t nx = (size_t)tn * Dn;
    const float nr = (float)r[nx + vb], nw = (float)w[nx + vb];
    const float nk = (float)kf[nx + vb], nkk = (float)kk[nx + vb];
    const float nab = (float)ab[nx + vb], nv = (float)v[nx + sb];
    const float sa = waveSum(S * kkj);          // DPP chain ~40 cyc
    S = (S * wj + vi * kj) - sa * abj;          // first part overlaps reduce
    const float o = waveSum(S * rj);
    if (j == 0) xo[(size_t)t * Dn + sb] = (__bf16)o;
    rj = nr; wj = nw; kj = nk; kkj = nkk; abj = nab; vi = nv;
  }
  st_out[(size_t)h * 4096 + i * 64 + j] = S;
}

// ---------------- post: per-head LN + bonus + gate -> bf16 ----------------

__global__ __launch_bounds__(256) void post_kernel(
    const __bf16* __restrict__ xo, const __bf16* __restrict__ v,
    const __bf16* __restrict__ g, const float* __restrict__ dot,
    const float* __restrict__ lnw, const float* __restrict__ lnb,
    __bf16* __restrict__ out) {
  const int t = blockIdx.x;
  const int lane = threadIdx.x & 63, wv = threadIdx.x >> 6;
#pragma unroll 1
  for (int c = 0; c < 8; ++c) {
    const int d = c * 256 + wv * 64 + lane;
    const size_t idx = (size_t)t * Dn + d;
    const float val = (float)xo[idx];
    const float mu = waveSum(val) * (1.f / 64.f);
    const float ctr = val - mu;
    const float var = waveSum(ctr * ctr) * (1.f / 64.f);
    float y = ctr * rsqrtf(var + 0.00064f);
    y = y * lnw[d] + lnb[d];
    const float res = (y + dot[t * Hn + (d >> 6)] * (float)v[idx]) * (float)g[idx];
    out[idx] = (__bf16)res;
  }
}

// ---------------- launcher ----------------

extern "C" void kernel_launch(void* const* d_in, const int* in_sizes, int n_in,
                              void* d_out, int out_size, void* d_ws, size_t ws_size,
                              hipStream_t stream) {
  (void)in_sizes; (void)n_in; (void)out_size; (void)ws_size;
  const float* x       = (const float*)d_in[0];
  const float* state1  = (const float*)d_in[1];
  const float* state2  = (const float*)d_in[2];
  const float* v_first = (const float*)d_in[3];
  const float* ln1_w   = (const float*)d_in[4];
  const float* ln1_b   = (const float*)d_in[5];
  const float* x_r     = (const float*)d_in[6];
  const float* x_w     = (const float*)d_in[7];
  const float* x_k     = (const float*)d_in[8];
  const float* x_v     = (const float*)d_in[9];
  const float* x_a     = (const float*)d_in[10];
  const float* x_g     = (const float*)d_in[11];
  const float* W_r     = (const float*)d_in[12];
  const float* W_k     = (const float*)d_in[13];
  const float* W_v     = (const float*)d_in[14];
  const float* W_o     = (const float*)d_in[15];
  const float* w1      = (const float*)d_in[16];
  const float* w2      = (const float*)d_in[17];
  const float* w0      = (const float*)d_in[18];
  const float* a1      = (const float*)d_in[19];
  const float* a2      = (const float*)d_in[20];
  const float* a0      = (const float*)d_in[21];
  const float* v1      = (const float*)d_in[22];
  const float* v2      = (const float*)d_in[23];
  const float* v0      = (const float*)d_in[24];
  const float* g1      = (const float*)d_in[25];
  const float* g2      = (const float*)d_in[26];
  const float* k_k     = (const float*)d_in[27];
  const float* k_a     = (const float*)d_in[28];
  const float* r_k     = (const float*)d_in[29];
  const float* lnx_w   = (const float*)d_in[30];
  const float* lnx_b   = (const float*)d_in[31];

  char* p = (char*)d_ws;
  const size_t MB = 1ull << 20;
  // 13 slots x 8 MB (each [T][D] bf16 = 8 MB exactly) + ~2.6 MB smalls = ~107 MB.
  __bf16* xn    = (__bf16*)(p + 0 * MB);
  __bf16* xobuf = (__bf16*)(p + 0 * MB);
  __bf16* xr_b  = (__bf16*)(p + 8 * MB);
  __bf16* Wo_b  = (__bf16*)(p + 8 * MB);
  __bf16* xw_b  = (__bf16*)(p + 16 * MB);
  __bf16* wdec  = (__bf16*)(p + 16 * MB);
  __bf16* xk_b  = (__bf16*)(p + 24 * MB);
  __bf16* abuf  = (__bf16*)(p + 24 * MB);
  __bf16* xo_b  = (__bf16*)(p + 24 * MB);
  __bf16* xv_b  = (__bf16*)(p + 32 * MB);
  __bf16* vbl   = (__bf16*)(p + 32 * MB);
  __bf16* xa_b  = (__bf16*)(p + 40 * MB);
  __bf16* gbuf  = (__bf16*)(p + 40 * MB);
  __bf16* xg_b  = (__bf16*)(p + 48 * MB);
  __bf16* kkbuf = (__bf16*)(p + 48 * MB);
  __bf16* Wr_b  = (__bf16*)(p + 56 * MB);
  __bf16* abbuf = (__bf16*)(p + 56 * MB);
  __bf16* Wk_b  = (__bf16*)(p + 64 * MB);
  __bf16* Wv_b  = (__bf16*)(p + 72 * MB);
  __bf16* rbuf  = (__bf16*)(p + 80 * MB);
  __bf16* kbuf  = (__bf16*)(p + 88 * MB);
  __bf16* vbuf  = (__bf16*)(p + 96 * MB);
  char* q = p + 104 * MB;                   // smalls, ~2.6 MB
  __bf16* yw  = (__bf16*)q; q += (size_t)Tn * 64 * 2;
  __bf16* ya  = (__bf16*)q; q += (size_t)Tn * 64 * 2;
  __bf16* yv  = (__bf16*)q; q += (size_t)Tn * 32 * 2;
  __bf16* yg  = (__bf16*)q; q += (size_t)Tn * 128 * 2;
  __bf16* w2T = (__bf16*)q; q += (size_t)Dn * 64 * 2;
  __bf16* a2T = (__bf16*)q; q += (size_t)Dn * 64 * 2;
  __bf16* v2T = (__bf16*)q; q += (size_t)Dn * 32 * 2;
  __bf16* g2T = (__bf16*)q; q += (size_t)Dn * 128 * 2;
  float*  dot = (float*)q;  q += (size_t)Tn * Hn * 4;

  float* out     = (float*)d_out;
  float* out_xnl = out + (size_t)Tn * Dn;
  float* out_st  = out_xnl + Dn;

  castw3_kernel<<<dim3(4096, 3), 256, 0, stream>>>(W_r, W_k, W_v, Wr_b, Wk_b, Wv_b);
  castT_kernel<<<2048, 256, 0, stream>>>(w2, a2, v2, g2, w2T, a2T, v2T, g2T);
  ln_kernel<<<2048, 256, 0, stream>>>(x, ln1_w, ln1_b, xn, out_xnl);
  mix_kernel<<<4096, 256, 0, stream>>>(xn, state1, x_r, x_w, x_k, x_v, x_a, x_g,
                                       xr_b, xw_b, xk_b, xv_b, xa_b, xg_b);
  gemm3_kernel<<<dim3(16, 16, 3), 256, 0, stream>>>(
      xr_b, xk_b, xv_b, Wr_b, Wk_b, Wv_b, rbuf, kbuf, vbuf);
  cast1_kernel<<<4096, 256, 0, stream>>>(W_o, Wo_b);  // S1: after gemm3 read xr_b
  lora1_kernel<<<dim3(256, 4), 256, 0, stream>>>(
      xw_b, xa_b, xv_b, xg_b, w1, a1, v1, g1, yw, ya, yv, yg);
  gemm_s2_kernel<<<dim3(16, 16, 4), 256, 0, stream>>>(
      yw, ya, yv, yg, w2T, a2T, v2T, g2T, w0, a0, v0, wdec, abuf, vbl, gbuf);
  prep_kernel<<<2048, 256, 0, stream>>>(rbuf, kbuf, vbuf, abuf, vbl, v_first,
                                        k_k, k_a, r_k, kkbuf, abbuf, dot);
  scan_kernel<<<dim3(32, 16), 256, 0, stream>>>(
      rbuf, wdec, kbuf, vbuf, kkbuf, abbuf, state2, xobuf, out_st);
  post_kernel<<<2048, 256, 0, stream>>>(xobuf, vbuf, gbuf, dot, lnx_w, lnx_b, xo_b);
  gemm_wo_kernel<<<dim3(16, 16), 256, 0, stream>>>(xo_b, Wo_b, x, out);
}